// Round 14
// baseline (146.829 us; speedup 1.0000x reference)
//
#include <hip/hip_runtime.h>
#include <hip/hip_bf16.h>
#include <math.h>

#define NB 8
#define NC 256
#define NHW 2304
#define NH 4
#define HD 64
#define CPG 8
#define GN_EPS 1e-5f

typedef __bf16 bf16;
typedef __bf16 bf16x4 __attribute__((ext_vector_type(4)));
typedef __bf16 bf16x8 __attribute__((ext_vector_type(8)));
typedef float f32x4 __attribute__((ext_vector_type(4)));
typedef float f32x16 __attribute__((ext_vector_type(16)));
typedef int i32x4 __attribute__((ext_vector_type(4)));
typedef unsigned int u32;

#define MFMA16(a, b, c) __builtin_amdgcn_mfma_f32_16x16x32_bf16(a, b, c, 0, 0, 0)
#define MFMA32(a, b, c) __builtin_amdgcn_mfma_f32_32x32x16_bf16(a, b, c, 0, 0, 0)

// fast 2^x: raw v_exp_f32 (exact for our |x| <~ 40 range)
__device__ __forceinline__ float fexp2(float x) {
  float r;
  asm("v_exp_f32 %0, %1" : "=v"(r) : "v"(x));
  return r;
}

// ---------------- fused: weight fp32->bf16 (blocks 0..767) + GroupNorm ------
__global__ __launch_bounds__(256) void k_pre(const float* __restrict__ x,
                                             const float* __restrict__ gw,
                                             const float* __restrict__ gb,
                                             const float* __restrict__ qw,
                                             const float* __restrict__ pw,
                                             bf16* __restrict__ xnt,
                                             bf16* __restrict__ wq,
                                             bf16* __restrict__ wp) {
  int t = threadIdx.x;
  if (blockIdx.x < 768) {
    int i = blockIdx.x * 256 + t;
    wq[i] = (bf16)qw[i];
    if (i < NC * NC) wp[i] = (bf16)pw[i];
    return;
  }
  int bid = blockIdx.x - 768;
  int b = bid >> 5;
  int g = bid & 31;
  int c0 = g * CPG;
  const float* xb = x + (b * NC + c0) * NHW;
  float v[CPG][9];
  float s = 0.f, s2 = 0.f;
#pragma unroll
  for (int cc = 0; cc < CPG; ++cc)
#pragma unroll
    for (int k = 0; k < 9; ++k) {
      float val = xb[cc * NHW + k * 256 + t];
      v[cc][k] = val;
      s += val;
      s2 += val * val;
    }
#pragma unroll
  for (int m = 1; m < 64; m <<= 1) {
    s += __shfl_xor(s, m);
    s2 += __shfl_xor(s2, m);
  }
  __shared__ float red[8];
  int wid = t >> 6;
  if ((t & 63) == 0) { red[wid] = s; red[4 + wid] = s2; }
  __syncthreads();
  s = red[0] + red[1] + red[2] + red[3];
  s2 = red[4] + red[5] + red[6] + red[7];
  const float inv_n = 1.0f / (CPG * NHW);
  float mean = s * inv_n;
  float var = s2 * inv_n - mean * mean;
  float rsq = rsqrtf(var + GN_EPS);
  float ka[CPG], kb[CPG];
#pragma unroll
  for (int cc = 0; cc < CPG; ++cc) {
    float wv = gw[c0 + cc];
    ka[cc] = wv * rsq;
    kb[cc] = gb[c0 + cc] - mean * rsq * wv;
  }
  bf16* dst = xnt + b * NHW * NC + c0;
#pragma unroll
  for (int k = 0; k < 9; ++k) {
    bf16x8 o;
#pragma unroll
    for (int cc = 0; cc < CPG; ++cc)
      o[cc] = (bf16)(v[cc][k] * ka[cc] + kb[cc]);
    *reinterpret_cast<bf16x8*>(dst + (k * 256 + t) * NC) = o;
  }
}

// ---------------- QKV GEMM: M=hw(i), N=768(o), K=256(c) ----------------
__global__ __launch_bounds__(256) void k_qkv(const bf16* __restrict__ xnt,
                                             const bf16* __restrict__ wq,
                                             const float* __restrict__ qkvb,
                                             bf16* __restrict__ qt,
                                             bf16* __restrict__ kt,
                                             bf16* __restrict__ vv) {
  int b = blockIdx.z;
  int i_base = blockIdx.x * 128;
  int o_base = blockIdx.y * 128;
  int t = threadIdx.x;
  int lane = t & 63, wid = t >> 6;
  int wm = (wid >> 1) * 64, wn = (wid & 1) * 64;
  int l15 = lane & 15, g = lane >> 4;
  const bool qk = (o_base < 512);
  const bf16* ab;
  const bf16* bb;
  if (qk) {
    ab = wq + (o_base + wm + l15) * NC + g * 8;
    bb = xnt + ((size_t)b * NHW + i_base + wn + l15) * NC + g * 8;
  } else {
    ab = xnt + ((size_t)b * NHW + i_base + wm + l15) * NC + g * 8;
    bb = wq + (o_base + wn + l15) * NC + g * 8;
  }
  f32x4 acc[4][4] = {};
#pragma unroll 2
  for (int kc = 0; kc < 8; ++kc) {
    bf16x8 af[4], bf[4];
#pragma unroll
    for (int mf = 0; mf < 4; ++mf)
      af[mf] = *reinterpret_cast<const bf16x8*>(ab + mf * 16 * NC + kc * 32);
#pragma unroll
    for (int nf = 0; nf < 4; ++nf)
      bf[nf] = *reinterpret_cast<const bf16x8*>(bb + nf * 16 * NC + kc * 32);
#pragma unroll
    for (int mf = 0; mf < 4; ++mf)
#pragma unroll
      for (int nf = 0; nf < 4; ++nf)
        acc[mf][nf] = MFMA16(af[mf], bf[nf], acc[mf][nf]);
  }
  if (qk) {
    const float qscale = 0.125f * 1.4426950408889634f;
#pragma unroll
    for (int mf = 0; mf < 4; ++mf) {
      int o0 = o_base + wm + mf * 16 + g * 4;  // rows o0..o0+3
      f32x4 b4 = *reinterpret_cast<const f32x4*>(qkvb + o0);
      bool isQ = (o0 < 256);
      float sc = isQ ? qscale : 1.0f;
      int oo = isQ ? o0 : o0 - 256;
      bf16* base = (isQ ? qt : kt) +
                   ((size_t)(b * NH + (oo >> 6)) * NHW) * HD + (oo & 63);
#pragma unroll
      for (int nf = 0; nf < 4; ++nf) {
        int i = i_base + wn + nf * 16 + l15;
        bf16x4 w;
#pragma unroll
        for (int r = 0; r < 4; ++r)
          w[r] = (bf16)((acc[mf][nf][r] + b4[r]) * sc);
        *reinterpret_cast<bf16x4*>(base + (size_t)i * HD) = w;
      }
    }
  } else {
#pragma unroll
    for (int nf = 0; nf < 4; ++nf) {
      int og = o_base + wn + nf * 16 + l15;  // 512..767
      float bias = qkvb[og];
      int o2 = og - 512;
      bf16* dp = vv + ((size_t)(b * NH + (o2 >> 6)) * HD + (o2 & 63)) * NHW +
                 i_base + wm + g * 4;
#pragma unroll
      for (int mf = 0; mf < 4; ++mf) {
        bf16x4 w;
#pragma unroll
        for (int r = 0; r < 4; ++r) w[r] = (bf16)(acc[mf][nf][r] + bias);
        *reinterpret_cast<bf16x4*>(dp + mf * 16) = w;
      }
    }
  }
}

// ---------------- flash attention: 64 q-rows/wave (halve LDS redundancy) ----
// r13 insight: all ig-waves with same jsub read IDENTICAL K/V fragments, so
// LDS read traffic = 4x staged bytes. Fix: each wave owns 64 q-rows (two
// 32-row groups qa/qb) against the SAME fragments -> fragment reads per
// block-tile halve, barriers per unit work halve, attn global traffic halves
// (576 blocks x 128i). Softmax_a (VALU) co-issues with QK_b (matrix pipe).
// Block = 256 thr, 4 waves = (ig, jsub); grid 576 = 8 XCD x 72 (bijective,
// 4 heads/XCD L2-resident). Inner per-group pipeline identical to r11/r13.
// launch_bounds(256,2): VGPR cap 256, ~190 est — spill-safe (r8 lesson).
__global__ __launch_bounds__(256, 2) void k_attn(const bf16* __restrict__ qt,
                                                 const bf16* __restrict__ kt,
                                                 const bf16* __restrict__ vv,
                                                 bf16* __restrict__ att) {
  __shared__ union SM {
    struct { bf16 k[2][4096]; bf16 v[2][4096]; } kv;  // 32 KB dbuf
    float m[2][64][17];                                // 8.7 KB (epilogue)
  } smem;

  const int tid = threadIdx.x;
  const int wid = tid >> 6, lane = tid & 63;
  const int l31 = lane & 31, g2 = lane >> 5;
  const int ig = wid & 1, jsub = wid >> 1;

  // bijective XCD swizzle: 576 blocks = 8 XCD x 72; each XCD gets 4 heads
  const int bid = blockIdx.x;
  const int wg = (bid & 7) * 72 + (bid >> 3);
  const int bh = wg / 18, it = wg % 18;
  const int b = bh >> 2, n = bh & 3;
  const int i0w = it * 128 + ig * 64;  // this wave: rows i0w..i0w+63

  const bf16* qb = qt + (size_t)bh * NHW * HD;
  const bf16* kb = kt + (size_t)bh * NHW * HD;
  const bf16* vb = vv + (size_t)bh * HD * NHW;

  // staging: thread (r0 = row 0..31, cs = 16B-chunk 0..7); rows r0 and r0+32
  const int r0 = tid >> 3, cs = tid & 7;
  const bf16* kg0 = kb + r0 * HD + cs * 8;
  const bf16* kg1 = kb + (r0 + 32) * HD + cs * 8;
  const bf16* vg0 = vb + (size_t)r0 * NHW + cs * 8;
  const bf16* vg1 = vb + (size_t)(r0 + 32) * NHW + cs * 8;
#define EOFF(c, row) ((c) * 512 + ((((row) + (c)) & 63) << 3))
  const int lw0 = EOFF(cs, r0);
  const int lw1 = EOFF(cs, r0 + 32);

  int ksw[4];
#pragma unroll
  for (int kk = 0; kk < 4; ++kk) ksw[kk] = EOFF(2 * kk + g2, jsub * 32 + l31);
  int vsw0[2], vsw1[2];
#pragma unroll
  for (int J = 0; J < 2; ++J) {
    int c = jsub * 4 + J * 2 + g2;
    vsw0[J] = EOFF(c, l31);
    vsw1[J] = EOFF(c, l31 + 32);
  }
#undef EOFF

  // Q fragments for both 32-row groups: B-frag col i=l31, d = 16*kk + 8*g2 + e
  bf16x8 qa[4], qbf[4];
#pragma unroll
  for (int kk = 0; kk < 4; ++kk) {
    qa[kk] = *reinterpret_cast<const bf16x8*>(qb + (i0w + l31) * HD + kk * 16 + g2 * 8);
    qbf[kk] = *reinterpret_cast<const bf16x8*>(qb + (i0w + 32 + l31) * HD + kk * 16 + g2 * 8);
  }

  f32x16 acc_a0 = {}, acc_a1 = {}, acc_b0 = {}, acc_b1 = {};
  float l_ra = 0.f, l_rb = 0.f;

  // prologue: stage tile 0 into buf 0
  {
    bf16x8 a = *reinterpret_cast<const bf16x8*>(kg0);
    bf16x8 c = *reinterpret_cast<const bf16x8*>(kg1);
    bf16x8 d = *reinterpret_cast<const bf16x8*>(vg0);
    bf16x8 e = *reinterpret_cast<const bf16x8*>(vg1);
    *reinterpret_cast<bf16x8*>(&smem.kv.k[0][lw0]) = a;
    *reinterpret_cast<bf16x8*>(&smem.kv.k[0][lw1]) = c;
    *reinterpret_cast<bf16x8*>(&smem.kv.v[0][lw0]) = d;
    *reinterpret_cast<bf16x8*>(&smem.kv.v[0][lw1]) = e;
  }
  asm volatile("s_waitcnt lgkmcnt(0)" ::: "memory");
  __builtin_amdgcn_s_barrier();

  for (int t = 0; t < 36; ++t) {
    const int cur = t & 1;
    bf16x8 kr0, kr1, vr0, vr1;
    if (t < 35) {  // issue next-tile global loads early (hide under compute)
      kr0 = *reinterpret_cast<const bf16x8*>(kg0 + (t + 1) * (64 * HD));
      kr1 = *reinterpret_cast<const bf16x8*>(kg1 + (t + 1) * (64 * HD));
      vr0 = *reinterpret_cast<const bf16x8*>(vg0 + (t + 1) * 64);
      vr1 = *reinterpret_cast<const bf16x8*>(vg1 + (t + 1) * 64);
    }
    const bf16* kc = smem.kv.k[cur];
    const bf16* vc = smem.kv.v[cur];

    // shared fragment reads (once per wave, serve BOTH q-row groups)
    bf16x8 kf[4], vf0[2], vf1[2];
#pragma unroll
    for (int kk = 0; kk < 4; ++kk)
      kf[kk] = *reinterpret_cast<const bf16x8*>(kc + ksw[kk]);
#pragma unroll
    for (int J = 0; J < 2; ++J) {
      vf0[J] = *reinterpret_cast<const bf16x8*>(vc + vsw0[J]);
      vf1[J] = *reinterpret_cast<const bf16x8*>(vc + vsw1[J]);
    }

    // QK for both groups (2 independent MFMA chains)
    f32x16 sa = {}, sb = {};
    __builtin_amdgcn_s_setprio(1);
#pragma unroll
    for (int kk = 0; kk < 4; ++kk) sa = MFMA32(kf[kk], qa[kk], sa);
#pragma unroll
    for (int kk = 0; kk < 4; ++kk) sb = MFMA32(kf[kk], qbf[kk], sb);
    __builtin_amdgcn_s_setprio(0);

    // softmax a (VALU) -> PV a; softmax b overlaps PV a on scheduler
    u32 P[8];
    {
      float la = 0.f, lb = 0.f;
#pragma unroll
      for (int m = 0; m < 8; ++m) {
        float e0 = fexp2(sa[2 * m]);
        float e1 = fexp2(sa[2 * m + 1]);
        la += e0;
        lb += e1;
        u32 pk;
        asm("v_cvt_pk_bf16_f32 %0, %1, %2" : "=v"(pk) : "v"(e0), "v"(e1));
        P[m] = pk;
      }
      l_ra += la + lb;
#pragma unroll
      for (int J = 0; J < 2; ++J) {
        u32 w0 = P[4 * J], w2 = P[4 * J + 2];
        asm("v_permlane32_swap_b32 %0, %1" : "+v"(w0), "+v"(w2));
        u32 w1 = P[4 * J + 1], w3 = P[4 * J + 3];
        asm("v_permlane32_swap_b32 %0, %1" : "+v"(w1), "+v"(w3));
        i32x4 wv;
        wv[0] = (int)w0; wv[1] = (int)w1; wv[2] = (int)w2; wv[3] = (int)w3;
        bf16x8 pf = __builtin_bit_cast(bf16x8, wv);
        __builtin_amdgcn_s_setprio(1);
        acc_a0 = MFMA32(vf0[J], pf, acc_a0);
        acc_a1 = MFMA32(vf1[J], pf, acc_a1);
        __builtin_amdgcn_s_setprio(0);
      }
    }
    {
      float la = 0.f, lb = 0.f;
#pragma unroll
      for (int m = 0; m < 8; ++m) {
        float e0 = fexp2(sb[2 * m]);
        float e1 = fexp2(sb[2 * m + 1]);
        la += e0;
        lb += e1;
        u32 pk;
        asm("v_cvt_pk_bf16_f32 %0, %1, %2" : "=v"(pk) : "v"(e0), "v"(e1));
        P[m] = pk;
      }
      l_rb += la + lb;
#pragma unroll
      for (int J = 0; J < 2; ++J) {
        u32 w0 = P[4 * J], w2 = P[4 * J + 2];
        asm("v_permlane32_swap_b32 %0, %1" : "+v"(w0), "+v"(w2));
        u32 w1 = P[4 * J + 1], w3 = P[4 * J + 3];
        asm("v_permlane32_swap_b32 %0, %1" : "+v"(w1), "+v"(w3));
        i32x4 wv;
        wv[0] = (int)w0; wv[1] = (int)w1; wv[2] = (int)w2; wv[3] = (int)w3;
        bf16x8 pf = __builtin_bit_cast(bf16x8, wv);
        __builtin_amdgcn_s_setprio(1);
        acc_b0 = MFMA32(vf0[J], pf, acc_b0);
        acc_b1 = MFMA32(vf1[J], pf, acc_b1);
        __builtin_amdgcn_s_setprio(0);
      }
    }

    if (t < 35) {  // write staged regs into other buffer
      const int nb = cur ^ 1;
      *reinterpret_cast<bf16x8*>(&smem.kv.k[nb][lw0]) = kr0;
      *reinterpret_cast<bf16x8*>(&smem.kv.k[nb][lw1]) = kr1;
      *reinterpret_cast<bf16x8*>(&smem.kv.v[nb][lw0]) = vr0;
      *reinterpret_cast<bf16x8*>(&smem.kv.v[nb][lw1]) = vr1;
    }
    asm volatile("s_waitcnt lgkmcnt(0)" ::: "memory");
    __builtin_amdgcn_s_barrier();
  }

  // merge jsub halves: plain add (zero-max => no rescale), 4 phases
#define MERGE(ACC, LSRC, HASL)                                                \
  if (jsub == 1) {                                                            \
    float* mb = smem.m[ig][lane];                                             \
    _Pragma("unroll") for (int e = 0; e < 16; ++e) mb[e] = ACC[e];            \
    if (HASL) mb[16] = LSRC;                                                  \
  }                                                                           \
  __syncthreads();                                                            \
  if (jsub == 0) {                                                            \
    const float* mb = smem.m[ig][lane];                                       \
    _Pragma("unroll") for (int e = 0; e < 16; ++e) ACC[e] += mb[e];           \
    if (HASL) LSRC += mb[16];                                                 \
  }                                                                           \
  __syncthreads();

  MERGE(acc_a0, l_ra, 1)
  MERGE(acc_a1, l_rb, 1)
  MERGE(acc_b0, l_ra, 0)
  MERGE(acc_b1, l_ra, 0)
#undef MERGE

  if (jsub == 0) {
    l_ra += __shfl_xor(l_ra, 32);
    l_rb += __shfl_xor(l_rb, 32);
    const float inva = 1.0f / l_ra;
    const float invb = 1.0f / l_rb;
    bf16* oa = att + ((size_t)(b * NHW) + i0w + l31) * NC + n * HD;
    bf16* ob = att + ((size_t)(b * NHW) + i0w + 32 + l31) * NC + n * HD;
#pragma unroll
    for (int rq = 0; rq < 4; ++rq) {
      bf16x4 w;
#pragma unroll
      for (int c = 0; c < 4; ++c) w[c] = (bf16)(acc_a0[rq * 4 + c] * inva);
      *reinterpret_cast<bf16x4*>(oa + 8 * rq + 4 * g2) = w;
#pragma unroll
      for (int c = 0; c < 4; ++c) w[c] = (bf16)(acc_a1[rq * 4 + c] * inva);
      *reinterpret_cast<bf16x4*>(oa + 32 + 8 * rq + 4 * g2) = w;
#pragma unroll
      for (int c = 0; c < 4; ++c) w[c] = (bf16)(acc_b0[rq * 4 + c] * invb);
      *reinterpret_cast<bf16x4*>(ob + 8 * rq + 4 * g2) = w;
#pragma unroll
      for (int c = 0; c < 4; ++c) w[c] = (bf16)(acc_b1[rq * 4 + c] * invb);
      *reinterpret_cast<bf16x4*>(ob + 32 + 8 * rq + 4 * g2) = w;
    }
  }
}

// ---------------- proj GEMM + bias + residual ----------------
__global__ __launch_bounds__(256) void k_proj(const bf16* __restrict__ att,
                                              const bf16* __restrict__ wp,
                                              const float* __restrict__ pb,
                                              const float* __restrict__ x,
                                              float* __restrict__ out) {
  int b = blockIdx.z;
  int i_base = blockIdx.x * 128;
  int o_base = blockIdx.y * 128;
  int t = threadIdx.x;
  int lane = t & 63, wid = t >> 6;
  int wm = (wid >> 1) * 64, wn = (wid & 1) * 64;
  int l15 = lane & 15, g = lane >> 4;
  const bf16* ab = wp + (o_base + wm + l15) * NC + g * 8;
  const bf16* bb = att + (b * NHW + i_base + wn + l15) * NC + g * 8;
  f32x4 acc[4][4] = {};
#pragma unroll 2
  for (int kc = 0; kc < 8; ++kc) {
    bf16x8 af[4], bf[4];
#pragma unroll
    for (int mf = 0; mf < 4; ++mf)
      af[mf] = *reinterpret_cast<const bf16x8*>(ab + mf * 16 * NC + kc * 32);
#pragma unroll
    for (int nf = 0; nf < 4; ++nf)
      bf[nf] = *reinterpret_cast<const bf16x8*>(bb + nf * 16 * NC + kc * 32);
#pragma unroll
    for (int mf = 0; mf < 4; ++mf)
#pragma unroll
      for (int nf = 0; nf < 4; ++nf)
        acc[mf][nf] = MFMA16(af[mf], bf[nf], acc[mf][nf]);
  }
  int orow0 = o_base + wm + g * 4;
#pragma unroll
  for (int mf = 0; mf < 4; ++mf)
#pragma unroll
    for (int r = 0; r < 4; ++r) {
      int o = orow0 + mf * 16 + r;
      float bias = pb[o];
      const float* xr = x + (b * NC + o) * NHW + i_base + wn;
      float* orow = out + (b * NC + o) * NHW + i_base + wn;
#pragma unroll
      for (int nf = 0; nf < 4; ++nf) {
        int i = nf * 16 + l15;
        orow[i] = acc[mf][nf][r] + bias + xr[i];
      }
    }
}

extern "C" void kernel_launch(void* const* d_in, const int* in_sizes, int n_in,
                              void* d_out, int out_size, void* d_ws, size_t ws_size,
                              hipStream_t stream) {
  const float* x    = (const float*)d_in[0];
  const float* gnw  = (const float*)d_in[1];
  const float* gnb  = (const float*)d_in[2];
  const float* qkvw = (const float*)d_in[3];
  const float* qkvb = (const float*)d_in[4];
  const float* pw   = (const float*)d_in[5];
  const float* pb   = (const float*)d_in[6];
  float* out = (float*)d_out;

  bf16* ws = (bf16*)d_ws;
  const size_t NE = (size_t)NB * NHW * NC;
  bf16* xnt = ws;
  bf16* qt  = ws + NE;
  bf16* kt  = ws + 2 * NE;
  bf16* vv  = ws + 3 * NE;
  bf16* att = ws + 4 * NE;
  bf16* wqb = ws + 5 * NE;
  bf16* wpb = wqb + 768 * 256;

  k_pre<<<1024, 256, 0, stream>>>(x, gnw, gnb, qkvw, pw, xnt, wqb, wpb);
  k_qkv<<<dim3(18, 6, NB), 256, 0, stream>>>(xnt, wqb, qkvb, qt, kt, vv);
  k_attn<<<576, 256, 0, stream>>>(qt, kt, vv, att);
  k_proj<<<dim3(18, 2, NB), 256, 0, stream>>>(att, wpb, pb, x, out);
}